// Round 12
// baseline (181.360 us; speedup 1.0000x reference)
//
#include <hip/hip_runtime.h>

#define NB   4
#define H_IN 14
#define W_IN 14
#define FIN  32
#define DI   8
#define F    32
#define C    288   // 3*3*32
#define DO   16
#define HO   12
#define WO   12
#define NPOS (NB*HO*WO)   // 576
#define EPS  1e-7f

#define CH   16            // c-chunks
#define CC   (C/CH)        // 18

#define W2_BYTES   ((size_t)F*C*DO*DI*4)       // 4,718,592
#define CENT_BYTES ((size_t)NPOS*F*DO*4)       // 1,179,648
#define PART_BYTES ((size_t)CH*CENT_BYTES)     // 18,874,368 (part1; part2 aliases)
#define OUT1_BYTES CENT_BYTES

__device__ __forceinline__ float dot8f(const float4 w0, const float4 w1,
                                       const float4 p0, const float4 p1) {
    return w0.x*p0.x + w0.y*p0.y + w0.z*p0.z + w0.w*p0.w
         + w1.x*p1.x + w1.y*p1.y + w1.z*p1.z + w1.w*p1.w;
}

__device__ __forceinline__ int xbase_of(int pos) {
    const int b = pos/(HO*WO), rem = pos%(HO*WO), ho = rem/WO, wo = rem%WO;
    return ((b*H_IN + ho)*W_IN + wo)*FIN*DI;
}

// stage xs[c_local][p][i] for 18 c's x 8 positions (4.6 KB)
__device__ __forceinline__ void stage_x(const float* __restrict__ x,
                                        float (*xs)[8][8],
                                        const int ch, const int pg, const int tid) {
    #pragma unroll
    for (int r = 0; r < 2; ++r) {
        const int idx = r*256 + tid;           // 288 float4 total
        if (idx < CC*16) {
            const int cl = idx >> 4;
            const int p  = (idx & 15) >> 1;
            const int h  = idx & 1;
            const int c  = ch*CC + cl;
            const int slab = c >> 5, fin = c & 31;
            const int kh = slab/3, kw = slab%3;
            const int off = xbase_of(pg*8 + p) + (kh*W_IN + kw)*FIN*DI + fin*DI + h*4;
            const float4 v = *(const float4*)(x + off);
            *(float4*)&xs[cl][p][h*4] = v;
        }
    }
}

// ---- transpose W[f][c][o][i] -> W2[c][o][f][i] --------------------------------
__global__ __launch_bounds__(256) void kernT(const float* __restrict__ Wt,
                                             float* __restrict__ W2) {
    const int idx4 = blockIdx.x*256 + threadIdx.x;
    const int i2 = idx4 & 1;
    const int f  = (idx4 >> 1) & 31;
    const int o  = (idx4 >> 6) & 15;
    const int c  = idx4 >> 10;
    ((float4*)W2)[idx4] = ((const float4*)Wt)[((size_t)(f*C + c)*DO + o)*2 + i2];
}

// ---- kern1: cent1 partials. thread=(f, o-pair); W software-pipelined. ---------
// writes part1[ch][pos][o][f]
__global__ __launch_bounds__(256, 4) void kern1n(const float* __restrict__ x,
                                                 const float* __restrict__ W2,
                                                 float* __restrict__ part1)
{
    __shared__ float xs[CC][8][8];
    const int tid = threadIdx.x;
    const int f  = tid & 31;
    const int og = tid >> 5;          // 0..7
    const int o0 = 2*og, o1 = o0 + 1;
    const int ch = blockIdx.x & (CH-1);
    const int pg = blockIdx.x >> 4;   // 0..71

    stage_x(x, xs, ch, pg, tid);

    const float4* W2f4 = (const float4*)W2;
    const int c0 = ch*CC;

    // prefetch W for first c
    const float4* wp0 = W2f4 + (size_t)c0*1024 + f*2;
    float4 w00 = wp0[o0*64], w01 = wp0[o0*64 + 1];
    float4 w10 = wp0[o1*64], w11 = wp0[o1*64 + 1];

    float acc0[8], acc1[8];
    #pragma unroll
    for (int p = 0; p < 8; ++p) { acc0[p] = 0.f; acc1[p] = 0.f; }

    __syncthreads();

    #pragma unroll 1
    for (int cl = 0; cl < CC; ++cl) {
        // issue next iteration's W loads (independent of this iteration's compute)
        const int cn = (cl < CC-1) ? cl + 1 : cl;
        const float4* wn = W2f4 + (size_t)(c0 + cn)*1024 + f*2;
        const float4 n00 = wn[o0*64], n01 = wn[o0*64 + 1];
        const float4 n10 = wn[o1*64], n11 = wn[o1*64 + 1];

        #pragma unroll
        for (int p = 0; p < 8; ++p) {
            const float4 a  = *(const float4*)&xs[cl][p][0];
            const float4 bq = *(const float4*)&xs[cl][p][4];
            acc0[p] += dot8f(w00, w01, a, bq);
            acc1[p] += dot8f(w10, w11, a, bq);
        }
        w00 = n00; w01 = n01; w10 = n10; w11 = n11;
    }
    #pragma unroll
    for (int p = 0; p < 8; ++p) {
        const size_t base = ((size_t)(ch*NPOS + pg*8 + p))*DO;
        part1[(base + o0)*F + f] = acc0[p];
        part1[(base + o1)*F + f] = acc1[p];
    }
}

// ---- kernO: out1[pos][f][o] = squash(sum_ch part1 / 32). ----------------------
__global__ __launch_bounds__(512) void kernO(const float* __restrict__ part1,
                                             float* __restrict__ out1)
{
    __shared__ float red[512];
    const int pos = blockIdx.x, tid = threadIdx.x;
    const int f = tid & 31, o = tid >> 5;

    float s = 0.f;
    #pragma unroll
    for (int k = 0; k < CH; ++k)
        s += part1[(size_t)(k*NPOS + pos)*512 + tid];
    s *= (1.f/32.f);

    red[tid] = s*s;
    __syncthreads();
    if (tid < 256) red[tid] += red[tid + 256];
    __syncthreads();
    if (tid < 128) red[tid] += red[tid + 128];
    __syncthreads();
    if (tid < 64)  red[tid] += red[tid + 64];
    __syncthreads();
    if (tid < 32) {
        const float sn = red[tid] + red[tid + 32];
        red[tid] = (sn/(1.f + sn)) * rsqrtf(sn + EPS);
    }
    __syncthreads();
    out1[(size_t)pos*512 + f*DO + o] = s * red[f];
}

// ---- kern2: thread=(f, o-pair); W software-pipelined; softmax via LDS. --------
// writes part2[ch][pos][o][f] (aliases part1).
__global__ __launch_bounds__(256) void kern2n(const float* __restrict__ x,
                                              const float* __restrict__ W2,
                                              const float* __restrict__ out1,
                                              float* __restrict__ part2)
{
    __shared__ float xs[CC][8][8];      // 4.6 KB
    __shared__ float red[2][4][8][32];  // 8 KB (dbuf)
    __shared__ float ccs[2][8][32];     // 2 KB (dbuf)

    const int tid = threadIdx.x;
    const int f  = tid & 31;
    const int og = tid >> 5;            // 0..7
    const int o0 = 2*og, o1 = o0 + 1;
    const int wv = tid >> 6;            // wave 0..3
    const int half = (tid >> 5) & 1;    // og parity within wave
    const int ch = blockIdx.x & (CH-1);
    const int pg = blockIdx.x >> 4;     // 0..71

    stage_x(x, xs, ch, pg, tid);

    // out1 values for (f, o0/o1) per position
    float u0[8], u1[8];
    #pragma unroll
    for (int p = 0; p < 8; ++p) {
        const float* up = out1 + (size_t)(pg*8 + p)*512 + f*DO;
        u0[p] = up[o0];
        u1[p] = up[o1];
    }

    const float4* W2f4 = (const float4*)W2;
    const int c0 = ch*CC;

    // prefetch W for first c
    const float4* wp0 = W2f4 + (size_t)c0*1024 + f*2;
    float4 w00 = wp0[o0*64], w01 = wp0[o0*64 + 1];
    float4 w10 = wp0[o1*64], w11 = wp0[o1*64 + 1];

    float acc0[8], acc1[8];
    #pragma unroll
    for (int p = 0; p < 8; ++p) { acc0[p] = 0.f; acc1[p] = 0.f; }

    __syncthreads();

    #pragma unroll 1
    for (int cl = 0; cl < CC; ++cl) {
        const int buf = cl & 1;

        // issue next iteration's W loads early
        const int cn = (cl < CC-1) ? cl + 1 : cl;
        const float4* wn = W2f4 + (size_t)(c0 + cn)*1024 + f*2;
        const float4 n00 = wn[o0*64], n01 = wn[o0*64 + 1];
        const float4 n10 = wn[o1*64], n11 = wn[o1*64 + 1];

        float pred0[8], pred1[8];
        #pragma unroll
        for (int p = 0; p < 8; ++p) {
            const float4 a  = *(const float4*)&xs[cl][p][0];
            const float4 bq = *(const float4*)&xs[cl][p][4];
            pred0[p] = dot8f(w00, w01, a, bq);
            pred1[p] = dot8f(w10, w11, a, bq);
        }

        // agr partial over this thread's two o's; combine og-pairs via xor-32
        #pragma unroll
        for (int p = 0; p < 8; ++p) {
            float ap = pred0[p]*u0[p] + pred1[p]*u1[p];
            ap += __shfl_xor(ap, 32);
            if (half == 0) red[buf][wv][p][f] = ap;
        }
        __syncthreads();

        // remapped role: (p2, f2); finish f-sum, softmax over f, publish cc
        {
            const int p2 = tid >> 5, f2 = tid & 31;
            const float agr = red[buf][0][p2][f2] + red[buf][1][p2][f2]
                            + red[buf][2][p2][f2] + red[buf][3][p2][f2];
            float m = agr;
            m = fmaxf(m, __shfl_xor(m, 1));
            m = fmaxf(m, __shfl_xor(m, 2));
            m = fmaxf(m, __shfl_xor(m, 4));
            m = fmaxf(m, __shfl_xor(m, 8));
            m = fmaxf(m, __shfl_xor(m, 16));
            const float e = __expf(agr - m);
            float s = e;
            s += __shfl_xor(s, 1);
            s += __shfl_xor(s, 2);
            s += __shfl_xor(s, 4);
            s += __shfl_xor(s, 8);
            s += __shfl_xor(s, 16);
            ccs[buf][p2][f2] = e / s;
        }
        __syncthreads();

        // back to (f, og): accumulate cent2
        #pragma unroll
        for (int p = 0; p < 8; ++p) {
            const float cv = ccs[buf][p][f];
            acc0[p] += cv*pred0[p];
            acc1[p] += cv*pred1[p];
        }
        w00 = n00; w01 = n01; w10 = n10; w11 = n11;
    }

    #pragma unroll
    for (int p = 0; p < 8; ++p) {
        const size_t base = ((size_t)(ch*NPOS + pg*8 + p))*DO;
        part2[(base + o0)*F + f] = acc0[p];
        part2[(base + o1)*F + f] = acc1[p];
    }
}

// ---- kern3: reduce cent2 partials ([ch][pos][o][f]), squash, store. -----------
__global__ __launch_bounds__(256) void kern3(const float* __restrict__ part2,
                                             float* __restrict__ out)
{
    const int tid = threadIdx.x;
    const int f = tid & 31, p = tid >> 5;
    const int pos = blockIdx.x*8 + p;

    float cent[DO];
    #pragma unroll
    for (int o = 0; o < DO; ++o) cent[o] = 0.f;
    #pragma unroll 1
    for (int k = 0; k < CH; ++k) {
        const float* s = part2 + (size_t)(k*NPOS + pos)*512 + f;
        #pragma unroll
        for (int o = 0; o < DO; ++o) cent[o] += s[o*F];
    }
    float sn = 0.f;
    #pragma unroll
    for (int o = 0; o < DO; ++o) sn += cent[o]*cent[o];
    const float sc = (sn/(1.f + sn)) * rsqrtf(sn + EPS);
    float* dst = out + ((size_t)pos*F + f)*DO;
    #pragma unroll
    for (int o = 0; o < DO; ++o) dst[o] = cent[o]*sc;
}

// -------- fp32 single-kernel fallback (if ws too small) ------------------------
__device__ __forceinline__ float dot8(const float4* __restrict__ w,
                                      const float4 p0, const float4 p1) {
    float4 a = w[0], b = w[1];
    return a.x*p0.x + a.y*p0.y + a.z*p0.z + a.w*p0.w
         + b.x*p1.x + b.y*p1.y + b.z*p1.z + b.w*p1.w;
}

__global__ __launch_bounds__(256) void capsule_kernel_f32(
    const float* __restrict__ x, const float* __restrict__ Wt,
    float* __restrict__ out)
{
    __shared__ float patch[C*DI];
    __shared__ float cent[F*DO];
    __shared__ float out1[F*DO];
    __shared__ float agr[F*C];
    __shared__ float scale_s[F];

    const int tid = threadIdx.x;
    const int pos = blockIdx.x;
    const int b   = pos / (HO*WO);
    const int rem = pos % (HO*WO);
    const int ho  = rem / WO;
    const int wo  = rem % WO;

    #pragma unroll
    for (int slab = 0; slab < 9; ++slab) {
        const int kh = slab / 3, kw = slab % 3;
        const float* src = x + (((b*H_IN + ho + kh)*W_IN + (wo + kw))*FIN)*DI;
        patch[slab*256 + tid] = src[tid];
    }
    __syncthreads();

    const float4* pv = (const float4*)patch;

    {
        const int fo0 = tid, fo1 = tid + 256;
        const int f0 = fo0 >> 4, o0 = fo0 & 15;
        const int f1 = fo1 >> 4, o1 = fo1 & 15;
        float acc0 = 0.f, acc1 = 0.f;
        for (int c = 0; c < C; ++c) {
            const float4 p0 = pv[c*2], p1 = pv[c*2+1];
            acc0 += dot8((const float4*)(Wt + ((f0*C + c)*DO + o0)*DI), p0, p1);
            acc1 += dot8((const float4*)(Wt + ((f1*C + c)*DO + o1)*DI), p0, p1);
        }
        cent[fo0] = acc0 * (1.f/32.f);
        cent[fo1] = acc1 * (1.f/32.f);
    }
    __syncthreads();

    if (tid < F) {
        float sn = 0.f;
        #pragma unroll
        for (int o = 0; o < DO; ++o) { float v = cent[tid*DO + o]; sn += v*v; }
        const float sc = (sn/(1.f + sn)) * rsqrtf(sn + EPS);
        #pragma unroll
        for (int o = 0; o < DO; ++o) out1[tid*DO + o] = cent[tid*DO + o] * sc;
    }
    __syncthreads();

    #pragma unroll 1
    for (int r = 0; r < (F*C)/256; ++r) {
        const int pp = tid + 256*r;
        const int f = pp / C, c = pp % C;
        const float4* wrow = (const float4*)(Wt + (f*C + c)*DO*DI);
        const float4 p0 = pv[c*2], p1 = pv[c*2+1];
        float a = 0.f;
        #pragma unroll
        for (int o = 0; o < DO; ++o) a += dot8(wrow + o*2, p0, p1) * out1[f*DO + o];
        agr[pp] = a;
    }
    __syncthreads();

    for (int c = tid; c < C; c += 256) {
        float m = -1e30f;
        #pragma unroll
        for (int f = 0; f < F; ++f) m = fmaxf(m, agr[f*C + c]);
        float s = 0.f;
        #pragma unroll
        for (int f = 0; f < F; ++f) {
            const float e = __expf(agr[f*C + c] - m);
            agr[f*C + c] = e; s += e;
        }
        const float inv = 1.f / s;
        #pragma unroll
        for (int f = 0; f < F; ++f) agr[f*C + c] *= inv;
    }
    __syncthreads();

    {
        const int fo0 = tid, fo1 = tid + 256;
        const int f0 = fo0 >> 4, o0 = fo0 & 15;
        const int f1 = fo1 >> 4, o1 = fo1 & 15;
        float acc0 = 0.f, acc1 = 0.f;
        for (int c = 0; c < C; ++c) {
            const float4 p0 = pv[c*2], p1 = pv[c*2+1];
            acc0 += agr[f0*C + c] * dot8((const float4*)(Wt + ((f0*C + c)*DO + o0)*DI), p0, p1);
            acc1 += agr[f1*C + c] * dot8((const float4*)(Wt + ((f1*C + c)*DO + o1)*DI), p0, p1);
        }
        cent[fo0] = acc0;
        cent[fo1] = acc1;
    }
    __syncthreads();

    if (tid < F) {
        float sn = 0.f;
        #pragma unroll
        for (int o = 0; o < DO; ++o) { float v = cent[tid*DO + o]; sn += v*v; }
        scale_s[tid] = (sn/(1.f + sn)) * rsqrtf(sn + EPS);
    }
    __syncthreads();

    out[pos*(F*DO) + tid]       = cent[tid]       * scale_s[tid >> 4];
    out[pos*(F*DO) + tid + 256] = cent[tid + 256] * scale_s[(tid >> 4) + 16];
}

extern "C" void kernel_launch(void* const* d_in, const int* in_sizes, int n_in,
                              void* d_out, int out_size, void* d_ws, size_t ws_size,
                              hipStream_t stream) {
    const float* x  = (const float*)d_in[0];
    const float* Wt = (const float*)d_in[1];
    float* out = (float*)d_out;

    if (ws_size >= W2_BYTES + PART_BYTES + OUT1_BYTES) {
        float* W2    = (float*)d_ws;
        float* part1 = (float*)((char*)d_ws + W2_BYTES);      // part2 aliases part1
        float* out1  = (float*)((char*)d_ws + W2_BYTES + PART_BYTES);
        kernT<<<(F*C*DO*DI)/4/256, 256, 0, stream>>>(Wt, W2);         // 1152 blocks
        kern1n<<<CH*(NPOS/8), 256, 0, stream>>>(x, W2, part1);        // 1152 blocks
        kernO<<<NPOS, 512, 0, stream>>>(part1, out1);                 // 576 blocks
        kern2n<<<CH*(NPOS/8), 256, 0, stream>>>(x, W2, out1, part1);  // 1152 blocks
        kern3<<<NPOS/8, 256, 0, stream>>>(part1, out);                // 72 blocks
    } else {
        capsule_kernel_f32<<<NPOS, 256, 0, stream>>>(x, Wt, out);
    }
}

// Round 13
// 145.998 us; speedup vs baseline: 1.2422x; 1.2422x over previous
//
#include <hip/hip_runtime.h>

#define NB   4
#define H_IN 14
#define W_IN 14
#define FIN  32
#define DI   8
#define F    32
#define C    288   // 3*3*32
#define DO   16
#define HO   12
#define WO   12
#define NPOS (NB*HO*WO)   // 576
#define EPS  1e-7f

#define CH   16            // c-chunks
#define CC   (C/CH)        // 18

#define XELE  (NB*H_IN*W_IN*FIN*DI)            // 200,704
#define W2H_BYTES  ((size_t)F*C*DO*DI*2)       // 2,359,296
#define XH_BYTES   ((size_t)XELE*2)            // 401,408
#define CENT_BYTES ((size_t)NPOS*F*DO*4)       // 1,179,648
#define PART_BYTES ((size_t)CH*CENT_BYTES)     // 18,874,368 (part1; part2 aliases)
#define OUT1_BYTES CENT_BYTES

typedef _Float16 h2 __attribute__((ext_vector_type(2)));

__device__ __forceinline__ unsigned int pack2(float a, float b) {
    h2 v; v.x = (_Float16)a; v.y = (_Float16)b;
    return __builtin_bit_cast(unsigned int, v);
}

// 8-term fp16 dot with fp32 accumulate
__device__ __forceinline__ float dot8h(const uint4 w, const uint4 v, float acc) {
#if __has_builtin(__builtin_amdgcn_fdot2)
    acc = __builtin_amdgcn_fdot2(__builtin_bit_cast(h2, w.x), __builtin_bit_cast(h2, v.x), acc, false);
    acc = __builtin_amdgcn_fdot2(__builtin_bit_cast(h2, w.y), __builtin_bit_cast(h2, v.y), acc, false);
    acc = __builtin_amdgcn_fdot2(__builtin_bit_cast(h2, w.z), __builtin_bit_cast(h2, v.z), acc, false);
    acc = __builtin_amdgcn_fdot2(__builtin_bit_cast(h2, w.w), __builtin_bit_cast(h2, v.w), acc, false);
#else
    const h2 w0 = __builtin_bit_cast(h2, w.x), v0 = __builtin_bit_cast(h2, v.x);
    const h2 w1 = __builtin_bit_cast(h2, w.y), v1 = __builtin_bit_cast(h2, v.y);
    const h2 w2 = __builtin_bit_cast(h2, w.z), v2 = __builtin_bit_cast(h2, v.z);
    const h2 w3 = __builtin_bit_cast(h2, w.w), v3 = __builtin_bit_cast(h2, v.w);
    acc += (float)w0.x*(float)v0.x + (float)w0.y*(float)v0.y
         + (float)w1.x*(float)v1.x + (float)w1.y*(float)v1.y
         + (float)w2.x*(float)v2.x + (float)w2.y*(float)v2.y
         + (float)w3.x*(float)v3.x + (float)w3.y*(float)v3.y;
#endif
    return acc;
}

__device__ __forceinline__ int xbase_of(int pos) {
    const int b = pos/(HO*WO), rem = pos%(HO*WO), ho = rem/WO, wo = rem%WO;
    return ((b*H_IN + ho)*W_IN + wo)*FIN*DI;
}

// stage xs4[cl][p] = 8 halves of x for (c, pos) — 144 uint4 = 2.3 KB
__device__ __forceinline__ void stage_xh(const unsigned short* __restrict__ xh,
                                         uint4 (*xs4)[8],
                                         const int ch, const int pg, const int tid) {
    if (tid < CC*8) {
        const int cl = tid >> 3, p = tid & 7;
        const int c  = ch*CC + cl;
        const int slab = c >> 5, fin = c & 31;
        const int kh = slab/3, kw = slab%3;
        const int off = xbase_of(pg*8 + p) + (kh*W_IN + kw)*FIN*DI + fin*DI;
        xs4[cl][p] = *(const uint4*)(xh + off);
    }
}

// ---- convert W[f][c][o][i] fp32 -> W2h[c][o][f][i] fp16 -----------------------
__global__ __launch_bounds__(256) void kernTh(const float* __restrict__ Wt,
                                              unsigned short* __restrict__ W2h) {
    const int idx = blockIdx.x*256 + threadIdx.x;  // (c*DO+o)*F+f, 147456 total
    const int f = idx & 31, o = (idx >> 5) & 15, c = idx >> 9;
    const float* src = Wt + ((size_t)(f*C + c)*DO + o)*DI;
    const float4 a = *(const float4*)src;
    const float4 b = *(const float4*)(src + 4);
    uint4 r;
    r.x = pack2(a.x, a.y); r.y = pack2(a.z, a.w);
    r.z = pack2(b.x, b.y); r.w = pack2(b.z, b.w);
    ((uint4*)W2h)[idx] = r;
}

// ---- convert x fp32 -> xh fp16 (same layout) ----------------------------------
__global__ __launch_bounds__(256) void kernXh(const float* __restrict__ x,
                                              unsigned short* __restrict__ xh) {
    const int i = blockIdx.x*256 + threadIdx.x;    // one float4 -> 4 halves
    const float4 v = ((const float4*)x)[i];
    uint2 o;
    o.x = pack2(v.x, v.y); o.y = pack2(v.z, v.w);
    ((uint2*)xh)[i] = o;
}

// ---- kern1: cent1 partials. thread=(f, o-pair), 8 positions. fp16 dots. -------
// writes part1[ch][pos][o][f] fp32
__global__ __launch_bounds__(256, 4) void kern1n(const unsigned short* __restrict__ xh,
                                                 const unsigned short* __restrict__ W2h,
                                                 float* __restrict__ part1)
{
    __shared__ uint4 xs4[CC][8];
    const int tid = threadIdx.x;
    const int f  = tid & 31;
    const int og = tid >> 5;          // 0..7
    const int o0 = 2*og, o1 = o0 + 1;
    const int ch = blockIdx.x & (CH-1);
    const int pg = blockIdx.x >> 4;   // 0..71

    stage_xh(xh, xs4, ch, pg, tid);
    __syncthreads();

    const uint4* W2h4 = (const uint4*)W2h;
    const int c0 = ch*CC;

    float acc0[8], acc1[8];
    #pragma unroll
    for (int p = 0; p < 8; ++p) { acc0[p] = 0.f; acc1[p] = 0.f; }

    #pragma unroll 1
    for (int cl = 0; cl < CC; ++cl) {
        const int c = c0 + cl;
        const uint4 w0 = W2h4[(size_t)(c*DO + o0)*F + f];
        const uint4 w1 = W2h4[(size_t)(c*DO + o1)*F + f];
        #pragma unroll
        for (int p = 0; p < 8; ++p) {
            const uint4 xv = xs4[cl][p];
            acc0[p] = dot8h(w0, xv, acc0[p]);
            acc1[p] = dot8h(w1, xv, acc1[p]);
        }
    }
    #pragma unroll
    for (int p = 0; p < 8; ++p) {
        const size_t base = ((size_t)(ch*NPOS + pg*8 + p))*DO;
        part1[(base + o0)*F + f] = acc0[p];
        part1[(base + o1)*F + f] = acc1[p];
    }
}

// ---- kernO: out1[pos][f][o] = squash(sum_ch part1 / 32). ----------------------
__global__ __launch_bounds__(512) void kernO(const float* __restrict__ part1,
                                             float* __restrict__ out1)
{
    __shared__ float red[512];
    const int pos = blockIdx.x, tid = threadIdx.x;
    const int f = tid & 31, o = tid >> 5;

    float s = 0.f;
    #pragma unroll
    for (int k = 0; k < CH; ++k)
        s += part1[(size_t)(k*NPOS + pos)*512 + tid];
    s *= (1.f/32.f);

    red[tid] = s*s;
    __syncthreads();
    if (tid < 256) red[tid] += red[tid + 256];
    __syncthreads();
    if (tid < 128) red[tid] += red[tid + 128];
    __syncthreads();
    if (tid < 64)  red[tid] += red[tid + 64];
    __syncthreads();
    if (tid < 32) {
        const float sn = red[tid] + red[tid + 32];
        red[tid] = (sn/(1.f + sn)) * rsqrtf(sn + EPS);
    }
    __syncthreads();
    out1[(size_t)pos*512 + f*DO + o] = s * red[f];
}

// ---- kern2: thread=(f, o-pair); fp16 dots; softmax via LDS round-trip. --------
// writes part2[ch][pos][o][f] fp32 (aliases part1)
__global__ __launch_bounds__(256) void kern2n(const unsigned short* __restrict__ xh,
                                              const unsigned short* __restrict__ W2h,
                                              const float* __restrict__ out1,
                                              float* __restrict__ part2)
{
    __shared__ uint4 xs4[CC][8];        // 2.3 KB
    __shared__ float red[2][4][8][32];  // 8 KB (dbuf)
    __shared__ float ccs[2][8][32];     // 2 KB (dbuf)

    const int tid = threadIdx.x;
    const int f  = tid & 31;
    const int og = tid >> 5;            // 0..7
    const int o0 = 2*og, o1 = o0 + 1;
    const int wv = tid >> 6;            // wave 0..3
    const int half = (tid >> 5) & 1;    // og parity within wave
    const int ch = blockIdx.x & (CH-1);
    const int pg = blockIdx.x >> 4;     // 0..71

    stage_xh(xh, xs4, ch, pg, tid);

    // out1 values for (f, o0/o1) per position
    float u0[8], u1[8];
    #pragma unroll
    for (int p = 0; p < 8; ++p) {
        const float* up = out1 + (size_t)(pg*8 + p)*512 + f*DO;
        u0[p] = up[o0];
        u1[p] = up[o1];
    }

    const uint4* W2h4 = (const uint4*)W2h;
    const int c0 = ch*CC;

    float acc0[8], acc1[8];
    #pragma unroll
    for (int p = 0; p < 8; ++p) { acc0[p] = 0.f; acc1[p] = 0.f; }

    __syncthreads();

    #pragma unroll 1
    for (int cl = 0; cl < CC; ++cl) {
        const int c = c0 + cl;
        const int buf = cl & 1;
        const uint4 w0 = W2h4[(size_t)(c*DO + o0)*F + f];
        const uint4 w1 = W2h4[(size_t)(c*DO + o1)*F + f];

        float pred0[8], pred1[8];
        #pragma unroll
        for (int p = 0; p < 8; ++p) {
            const uint4 xv = xs4[cl][p];
            pred0[p] = dot8h(w0, xv, 0.f);
            pred1[p] = dot8h(w1, xv, 0.f);
        }

        // agr partial over this thread's two o's; combine og-pairs via xor-32
        #pragma unroll
        for (int p = 0; p < 8; ++p) {
            float ap = pred0[p]*u0[p] + pred1[p]*u1[p];
            ap += __shfl_xor(ap, 32);
            if (half == 0) red[buf][wv][p][f] = ap;
        }
        __syncthreads();

        // remapped role: (p2, f2); finish f-sum, softmax over f, publish cc
        {
            const int p2 = tid >> 5, f2 = tid & 31;
            const float agr = red[buf][0][p2][f2] + red[buf][1][p2][f2]
                            + red[buf][2][p2][f2] + red[buf][3][p2][f2];
            float m = agr;
            m = fmaxf(m, __shfl_xor(m, 1));
            m = fmaxf(m, __shfl_xor(m, 2));
            m = fmaxf(m, __shfl_xor(m, 4));
            m = fmaxf(m, __shfl_xor(m, 8));
            m = fmaxf(m, __shfl_xor(m, 16));
            const float e = __expf(agr - m);
            float s = e;
            s += __shfl_xor(s, 1);
            s += __shfl_xor(s, 2);
            s += __shfl_xor(s, 4);
            s += __shfl_xor(s, 8);
            s += __shfl_xor(s, 16);
            ccs[buf][p2][f2] = e / s;
        }
        __syncthreads();

        // back to (f, og): accumulate cent2
        #pragma unroll
        for (int p = 0; p < 8; ++p) {
            const float cv = ccs[buf][p][f];
            acc0[p] += cv*pred0[p];
            acc1[p] += cv*pred1[p];
        }
    }

    #pragma unroll
    for (int p = 0; p < 8; ++p) {
        const size_t base = ((size_t)(ch*NPOS + pg*8 + p))*DO;
        part2[(base + o0)*F + f] = acc0[p];
        part2[(base + o1)*F + f] = acc1[p];
    }
}

// ---- kern3: reduce cent2 partials ([ch][pos][o][f]), squash, store. -----------
__global__ __launch_bounds__(256) void kern3(const float* __restrict__ part2,
                                             float* __restrict__ out)
{
    const int tid = threadIdx.x;
    const int f = tid & 31, p = tid >> 5;
    const int pos = blockIdx.x*8 + p;

    float cent[DO];
    #pragma unroll
    for (int o = 0; o < DO; ++o) cent[o] = 0.f;
    #pragma unroll 1
    for (int k = 0; k < CH; ++k) {
        const float* s = part2 + (size_t)(k*NPOS + pos)*512 + f;
        #pragma unroll
        for (int o = 0; o < DO; ++o) cent[o] += s[o*F];
    }
    float sn = 0.f;
    #pragma unroll
    for (int o = 0; o < DO; ++o) sn += cent[o]*cent[o];
    const float sc = (sn/(1.f + sn)) * rsqrtf(sn + EPS);
    float* dst = out + ((size_t)pos*F + f)*DO;
    #pragma unroll
    for (int o = 0; o < DO; ++o) dst[o] = cent[o]*sc;
}

// -------- fp32 single-kernel fallback (if ws too small) ------------------------
__device__ __forceinline__ float dot8(const float4* __restrict__ w,
                                      const float4 p0, const float4 p1) {
    float4 a = w[0], b = w[1];
    return a.x*p0.x + a.y*p0.y + a.z*p0.z + a.w*p0.w
         + b.x*p1.x + b.y*p1.y + b.z*p1.z + b.w*p1.w;
}

__global__ __launch_bounds__(256) void capsule_kernel_f32(
    const float* __restrict__ x, const float* __restrict__ Wt,
    float* __restrict__ out)
{
    __shared__ float patch[C*DI];
    __shared__ float cent[F*DO];
    __shared__ float out1[F*DO];
    __shared__ float agr[F*C];
    __shared__ float scale_s[F];

    const int tid = threadIdx.x;
    const int pos = blockIdx.x;
    const int b   = pos / (HO*WO);
    const int rem = pos % (HO*WO);
    const int ho  = rem / WO;
    const int wo  = rem % WO;

    #pragma unroll
    for (int slab = 0; slab < 9; ++slab) {
        const int kh = slab / 3, kw = slab % 3;
        const float* src = x + (((b*H_IN + ho + kh)*W_IN + (wo + kw))*FIN)*DI;
        patch[slab*256 + tid] = src[tid];
    }
    __syncthreads();

    const float4* pv = (const float4*)patch;

    {
        const int fo0 = tid, fo1 = tid + 256;
        const int f0 = fo0 >> 4, o0 = fo0 & 15;
        const int f1 = fo1 >> 4, o1 = fo1 & 15;
        float acc0 = 0.f, acc1 = 0.f;
        for (int c = 0; c < C; ++c) {
            const float4 p0 = pv[c*2], p1 = pv[c*2+1];
            acc0 += dot8((const float4*)(Wt + ((f0*C + c)*DO + o0)*DI), p0, p1);
            acc1 += dot8((const float4*)(Wt + ((f1*C + c)*DO + o1)*DI), p0, p1);
        }
        cent[fo0] = acc0 * (1.f/32.f);
        cent[fo1] = acc1 * (1.f/32.f);
    }
    __syncthreads();

    if (tid < F) {
        float sn = 0.f;
        #pragma unroll
        for (int o = 0; o < DO; ++o) { float v = cent[tid*DO + o]; sn += v*v; }
        const float sc = (sn/(1.f + sn)) * rsqrtf(sn + EPS);
        #pragma unroll
        for (int o = 0; o < DO; ++o) out1[tid*DO + o] = cent[tid*DO + o] * sc;
    }
    __syncthreads();

    #pragma unroll 1
    for (int r = 0; r < (F*C)/256; ++r) {
        const int pp = tid + 256*r;
        const int f = pp / C, c = pp % C;
        const float4* wrow = (const float4*)(Wt + (f*C + c)*DO*DI);
        const float4 p0 = pv[c*2], p1 = pv[c*2+1];
        float a = 0.f;
        #pragma unroll
        for (int o = 0; o < DO; ++o) a += dot8(wrow + o*2, p0, p1) * out1[f*DO + o];
        agr[pp] = a;
    }
    __syncthreads();

    for (int c = tid; c < C; c += 256) {
        float m = -1e30f;
        #pragma unroll
        for (int f = 0; f < F; ++f) m = fmaxf(m, agr[f*C + c]);
        float s = 0.f;
        #pragma unroll
        for (int f = 0; f < F; ++f) {
            const float e = __expf(agr[f*C + c] - m);
            agr[f*C + c] = e; s += e;
        }
        const float inv = 1.f / s;
        #pragma unroll
        for (int f = 0; f < F; ++f) agr[f*C + c] *= inv;
    }
    __syncthreads();

    {
        const int fo0 = tid, fo1 = tid + 256;
        const int f0 = fo0 >> 4, o0 = fo0 & 15;
        const int f1 = fo1 >> 4, o1 = fo1 & 15;
        float acc0 = 0.f, acc1 = 0.f;
        for (int c = 0; c < C; ++c) {
            const float4 p0 = pv[c*2], p1 = pv[c*2+1];
            acc0 += agr[f0*C + c] * dot8((const float4*)(Wt + ((f0*C + c)*DO + o0)*DI), p0, p1);
            acc1 += agr[f1*C + c] * dot8((const float4*)(Wt + ((f1*C + c)*DO + o1)*DI), p0, p1);
        }
        cent[fo0] = acc0;
        cent[fo1] = acc1;
    }
    __syncthreads();

    if (tid < F) {
        float sn = 0.f;
        #pragma unroll
        for (int o = 0; o < DO; ++o) { float v = cent[tid*DO + o]; sn += v*v; }
        scale_s[tid] = (sn/(1.f + sn)) * rsqrtf(sn + EPS);
    }
    __syncthreads();

    out[pos*(F*DO) + tid]       = cent[tid]       * scale_s[tid >> 4];
    out[pos*(F*DO) + tid + 256] = cent[tid + 256] * scale_s[(tid >> 4) + 16];
}

extern "C" void kernel_launch(void* const* d_in, const int* in_sizes, int n_in,
                              void* d_out, int out_size, void* d_ws, size_t ws_size,
                              hipStream_t stream) {
    const float* x  = (const float*)d_in[0];
    const float* Wt = (const float*)d_in[1];
    float* out = (float*)d_out;

    if (ws_size >= W2H_BYTES + XH_BYTES + PART_BYTES + OUT1_BYTES) {
        unsigned short* W2h = (unsigned short*)d_ws;
        unsigned short* xh  = (unsigned short*)((char*)d_ws + W2H_BYTES);
        float* part1 = (float*)((char*)d_ws + W2H_BYTES + XH_BYTES);   // part2 aliases
        float* out1  = (float*)((char*)d_ws + W2H_BYTES + XH_BYTES + PART_BYTES);
        kernTh<<<(F*C*DO)/256*1, 256, 0, stream>>>(Wt, W2h);          // 576 blocks
        kernXh<<<XELE/4/256, 256, 0, stream>>>(x, xh);                 // 196 blocks
        kern1n<<<CH*(NPOS/8), 256, 0, stream>>>(xh, W2h, part1);       // 1152 blocks
        kernO<<<NPOS, 512, 0, stream>>>(part1, out1);                  // 576 blocks
        kern2n<<<CH*(NPOS/8), 256, 0, stream>>>(xh, W2h, out1, part1); // 1152 blocks
        kern3<<<NPOS/8, 256, 0, stream>>>(part1, out);                 // 72 blocks
    } else {
        capsule_kernel_f32<<<NPOS, 256, 0, stream>>>(x, Wt, out);
    }
}